// Round 8
// baseline (158.850 us; speedup 1.0000x reference)
//
#include <hip/hip_runtime.h>

#define LSZ 1024
#define EPS 1e-8f
#define NBLK 4096

struct c32 { float re, im; };

__device__ __forceinline__ c32 cmul(c32 a, c32 b) {
    return { a.re * b.re - a.im * b.im, a.re * b.im + a.im * b.re };
}
// a * conj(b)
__device__ __forceinline__ c32 cmulc(c32 a, c32 b) {
    return { a.re * b.re + a.im * b.im, a.im * b.re - a.re * b.im };
}
__device__ __forceinline__ c32 cadd(c32 a, c32 b) {
    return { a.re + b.re, a.im + b.im };
}

// g = cos(n) I + i sinc(n) (theta . sigma). Native sin/cos/rcp: theta norms
// are <= ~7 (3 gaussians), safely in fast range; error ~1e-6 << 8e-2 thresh.
__device__ __forceinline__ void make_g(float t1, float t2, float t3, c32 g[2][2]) {
    float n2 = t1 * t1 + t2 * t2 + t3 * t3;
    float n  = __builtin_amdgcn_sqrtf(n2);
    float c  = __cosf(n);
    float sn = __sinf(n);
    float s  = (n > EPS) ? (sn * __builtin_amdgcn_rcpf(n)) : 1.0f;
    float a1 = s * t1, a2 = s * t2, a3 = s * t3;
    g[0][0] = {  c,  a3 };
    g[0][1] = {  a2, a1 };
    g[1][0] = { -a2, a1 };
    g[1][1] = {  c, -a3 };
}

// Ut = g @ M @ gn^dagger ; return sum |P - Ut|^2 over the 4 entries
__device__ __forceinline__ float site_mu_loss(const c32 g[2][2], const c32 gn[2][2],
                                              float4 m0, float4 m1,
                                              float4 p0, float4 p1) {
    c32 M[2][2] = { { { m0.x, m0.y }, { m0.z, m0.w } },
                    { { m1.x, m1.y }, { m1.z, m1.w } } };
    c32 P[2][2] = { { { p0.x, p0.y }, { p0.z, p0.w } },
                    { { p1.x, p1.y }, { p1.z, p1.w } } };
    c32 T[2][2];
#pragma unroll
    for (int a = 0; a < 2; ++a)
#pragma unroll
        for (int cc = 0; cc < 2; ++cc)
            T[a][cc] = cadd(cmul(g[a][0], M[0][cc]), cmul(g[a][1], M[1][cc]));

    float acc = 0.0f;
#pragma unroll
    for (int a = 0; a < 2; ++a)
#pragma unroll
        for (int d = 0; d < 2; ++d) {
            c32 ut = cadd(cmulc(T[a][0], gn[d][0]), cmulc(T[a][1], gn[d][1]));
            float dr = P[a][d].re - ut.re;
            float di = P[a][d].im - ut.im;
            acc += dr * dr + di * di;
        }
    return acc;
}

// One block = one quarter-row (x uniform, y in [y0, y0+256)). Theta staged
// into LDS with fully-coalesced dword loads: kills the 9 stride-12 scalar
// global loads per thread (they were ~46% of the wave's cache-line requests
// for only 8% of the bytes). Per-thread VMEM: 17 -> ~8.5 instructions.
__global__ __launch_bounds__(256) void gauge_loss_kernel(
    const float* __restrict__ theta,
    const float* __restrict__ U_pred,
    const float* __restrict__ U_true,
    float* __restrict__ partial) {
    __shared__ float thA[257 * 3];   // row x : y0 .. y0+256 (last wraps)
    __shared__ float thB[256 * 3];   // row x+1: y0 .. y0+255

    const int b = blockIdx.x;
    const int t = threadIdx.x;
    const int x  = b >> 2;
    const int y0 = (b & 3) << 8;
    const int xp = (x + 1) & (LSZ - 1);
    const int idx = (b << 8) + t;    // site index = x*1024 + y0 + t

    // ---- issue U loads first (independent of LDS staging) ----
    const float4* Ut4 = (const float4*)U_true + (size_t)idx * 4;
    const float4* Up4 = (const float4*)U_pred + (size_t)idx * 4;
    float4 t0 = Ut4[0], t1 = Ut4[1], t2 = Ut4[2], t3 = Ut4[3];
    float4 p0 = Up4[0], p1 = Up4[1], p2 = Up4[2], p3 = Up4[3];

    // ---- stage theta rows (768 contiguous dwords each, coalesced) ----
    const float* rowA = theta + (size_t)(x  * LSZ + y0) * 3;
    const float* rowB = theta + (size_t)(xp * LSZ + y0) * 3;
#pragma unroll
    for (int i = 0; i < 3; ++i) {
        thA[i * 256 + t] = rowA[i * 256 + t];
        thB[i * 256 + t] = rowB[i * 256 + t];
    }
    if (t == 0) {
        const float* w = theta + (size_t)(x * LSZ + ((y0 + 256) & (LSZ - 1))) * 3;
        thA[768] = w[0]; thA[769] = w[1]; thA[770] = w[2];
    }
    __syncthreads();

    // ---- g matrices from LDS ----
    c32 g[2][2], gx[2][2], gy[2][2];
    make_g(thA[3 * t],       thA[3 * t + 1],       thA[3 * t + 2],       g);   // (x,   y)
    make_g(thB[3 * t],       thB[3 * t + 1],       thB[3 * t + 2],       gx);  // (x+1, y)
    make_g(thA[3 * (t + 1)], thA[3 * (t + 1) + 1], thA[3 * (t + 1) + 2], gy);  // (x,   y+1)

    float acc = site_mu_loss(g, gx, t0, t1, p0, p1)    // mu = 0
              + site_mu_loss(g, gy, t2, t3, p2, p3);   // mu = 1

    // fold: mean over 4 entries (1/4) and final /(L*L*2)
    acc *= (1.0f / (8.0f * (float)LSZ * (float)LSZ));

    // wave (64-lane) shuffle reduction
#pragma unroll
    for (int off = 32; off > 0; off >>= 1)
        acc += __shfl_down(acc, off, 64);

    __shared__ float wave_sums[4];
    int lane = threadIdx.x & 63;
    int wave = threadIdx.x >> 6;
    if (lane == 0) wave_sums[wave] = acc;
    __syncthreads();
    if (threadIdx.x == 0)
        partial[blockIdx.x] = wave_sums[0] + wave_sums[1] + wave_sums[2] + wave_sums[3];
}

__global__ __launch_bounds__(256) void reduce_kernel(const float* __restrict__ partial,
                                                     float* __restrict__ out) {
    float s = 0.0f;
#pragma unroll
    for (int i = 0; i < NBLK / 256; ++i)
        s += partial[i * 256 + threadIdx.x];

#pragma unroll
    for (int off = 32; off > 0; off >>= 1)
        s += __shfl_down(s, off, 64);

    __shared__ float wave_sums[4];
    int lane = threadIdx.x & 63;
    int wave = threadIdx.x >> 6;
    if (lane == 0) wave_sums[wave] = s;
    __syncthreads();
    if (threadIdx.x == 0)
        out[0] = wave_sums[0] + wave_sums[1] + wave_sums[2] + wave_sums[3];
}

extern "C" void kernel_launch(void* const* d_in, const int* in_sizes, int n_in,
                              void* d_out, int out_size, void* d_ws, size_t ws_size,
                              hipStream_t stream) {
    const float* theta  = (const float*)d_in[0];
    const float* U_pred = (const float*)d_in[1];
    const float* U_true = (const float*)d_in[2];
    float* out = (float*)d_out;
    float* partial = (float*)d_ws;  // NBLK floats

    gauge_loss_kernel<<<NBLK, 256, 0, stream>>>(theta, U_pred, U_true, partial);
    reduce_kernel<<<1, 256, 0, stream>>>(partial, out);
}

// Round 9
// 154.927 us; speedup vs baseline: 1.0253x; 1.0253x over previous
//
#include <hip/hip_runtime.h>

#define LSZ 1024
#define EPS 1e-8f
#define NBLK 1024
#define SPT 4                      // sites per thread
#define STRIDE (NBLK * 256)        // 262144 threads

struct c32 { float re, im; };

__device__ __forceinline__ c32 cmul(c32 a, c32 b) {
    return { a.re * b.re - a.im * b.im, a.re * b.im + a.im * b.re };
}
// a * conj(b)
__device__ __forceinline__ c32 cmulc(c32 a, c32 b) {
    return { a.re * b.re + a.im * b.im, a.im * b.re - a.re * b.im };
}
__device__ __forceinline__ c32 cadd(c32 a, c32 b) {
    return { a.re + b.re, a.im + b.im };
}

// All data one thread needs for one site.
struct SitePayload {
    float4 t0, t1, t2, t3;   // U_true[site][mu=0,1]
    float4 p0, p1, p2, p3;   // U_pred[site][mu=0,1]
    float3 a, b, c;          // theta at (x,y), (x+1,y), (x,y+1)
};

__device__ __forceinline__ void issue_loads(int idx,
                                            const float* __restrict__ theta,
                                            const float* __restrict__ U_pred,
                                            const float* __restrict__ U_true,
                                            SitePayload& s) {
    int x = idx >> 10, y = idx & (LSZ - 1);
    int xp = (x + 1) & (LSZ - 1), yp = (y + 1) & (LSZ - 1);
    const float4* Ut4 = (const float4*)U_true + (size_t)idx * 4;
    const float4* Up4 = (const float4*)U_pred + (size_t)idx * 4;
    s.t0 = Ut4[0]; s.t1 = Ut4[1]; s.t2 = Ut4[2]; s.t3 = Ut4[3];
    s.p0 = Up4[0]; s.p1 = Up4[1]; s.p2 = Up4[2]; s.p3 = Up4[3];
    const float* ta = theta + 3 * (x  * LSZ + y);
    const float* tb = theta + 3 * (xp * LSZ + y);
    const float* tc = theta + 3 * (x  * LSZ + yp);
    s.a = make_float3(ta[0], ta[1], ta[2]);
    s.b = make_float3(tb[0], tb[1], tb[2]);
    s.c = make_float3(tc[0], tc[1], tc[2]);
}

// g = cos(n) I + i sinc(n) (theta . sigma). Native sin/cos/rcp: theta norms
// are <= ~7 (3 gaussians), safely in fast range; error ~1e-6 << 8e-2 thresh.
__device__ __forceinline__ void make_g(float3 t, c32 g[2][2]) {
    float n2 = t.x * t.x + t.y * t.y + t.z * t.z;
    float n  = __builtin_amdgcn_sqrtf(n2);
    float cc = __cosf(n);
    float sn = __sinf(n);
    float s  = (n > EPS) ? (sn * __builtin_amdgcn_rcpf(n)) : 1.0f;
    float a1 = s * t.x, a2 = s * t.y, a3 = s * t.z;
    g[0][0] = {  cc,  a3 };
    g[0][1] = {  a2,  a1 };
    g[1][0] = { -a2,  a1 };
    g[1][1] = {  cc, -a3 };
}

// Ut = g @ M @ gn^dagger ; return sum |P - Ut|^2 over the 4 entries
__device__ __forceinline__ float site_mu_loss(const c32 g[2][2], const c32 gn[2][2],
                                              float4 m0, float4 m1,
                                              float4 p0, float4 p1) {
    c32 M[2][2] = { { { m0.x, m0.y }, { m0.z, m0.w } },
                    { { m1.x, m1.y }, { m1.z, m1.w } } };
    c32 P[2][2] = { { { p0.x, p0.y }, { p0.z, p0.w } },
                    { { p1.x, p1.y }, { p1.z, p1.w } } };
    c32 T[2][2];
#pragma unroll
    for (int a = 0; a < 2; ++a)
#pragma unroll
        for (int cc = 0; cc < 2; ++cc)
            T[a][cc] = cadd(cmul(g[a][0], M[0][cc]), cmul(g[a][1], M[1][cc]));

    float acc = 0.0f;
#pragma unroll
    for (int a = 0; a < 2; ++a)
#pragma unroll
        for (int d = 0; d < 2; ++d) {
            c32 ut = cadd(cmulc(T[a][0], gn[d][0]), cmulc(T[a][1], gn[d][1]));
            float dr = P[a][d].re - ut.re;
            float di = P[a][d].im - ut.im;
            acc += dr * dr + di * di;
        }
    return acc;
}

__device__ __forceinline__ float site_loss(const SitePayload& s) {
    c32 g[2][2], gx[2][2], gy[2][2];
    make_g(s.a, g);
    make_g(s.b, gx);
    make_g(s.c, gy);
    return site_mu_loss(g, gx, s.t0, s.t1, s.p0, s.p1)    // mu = 0
         + site_mu_loss(g, gy, s.t2, s.t3, s.p2, s.p3);   // mu = 1
}

// Streaming grid-stride structure (the 6.3 TB/s memcpy ubench shape): each
// thread loops over SPT sites with register prefetch — site s+1's loads are
// issued before site s's compute, so compute fills the load latency and the
// per-wave head/tail latency is amortized SPT times. One-shot-per-thread
// kernels (R1-R8) were all pinned at ~48-51 us regardless of structure.
__global__ __launch_bounds__(256) void gauge_loss_kernel(
    const float* __restrict__ theta,
    const float* __restrict__ U_pred,
    const float* __restrict__ U_true,
    float* __restrict__ partial) {
    const int tid = blockIdx.x * 256 + threadIdx.x;

    SitePayload cur, nxt;
    issue_loads(tid, theta, U_pred, U_true, cur);

    float acc = 0.0f;
#pragma unroll
    for (int s = 0; s < SPT; ++s) {
        if (s + 1 < SPT)
            issue_loads(tid + (s + 1) * STRIDE, theta, U_pred, U_true, nxt);
        acc += site_loss(cur);
        cur = nxt;
    }

    // fold: mean over 4 entries (1/4) and final /(L*L*2)
    acc *= (1.0f / (8.0f * (float)LSZ * (float)LSZ));

    // wave (64-lane) shuffle reduction
#pragma unroll
    for (int off = 32; off > 0; off >>= 1)
        acc += __shfl_down(acc, off, 64);

    __shared__ float wave_sums[4];
    int lane = threadIdx.x & 63;
    int wave = threadIdx.x >> 6;
    if (lane == 0) wave_sums[wave] = acc;
    __syncthreads();
    if (threadIdx.x == 0)
        partial[blockIdx.x] = wave_sums[0] + wave_sums[1] + wave_sums[2] + wave_sums[3];
}

__global__ __launch_bounds__(256) void reduce_kernel(const float* __restrict__ partial,
                                                     float* __restrict__ out) {
    float s = 0.0f;
#pragma unroll
    for (int i = 0; i < NBLK / 256; ++i)
        s += partial[i * 256 + threadIdx.x];

#pragma unroll
    for (int off = 32; off > 0; off >>= 1)
        s += __shfl_down(s, off, 64);

    __shared__ float wave_sums[4];
    int lane = threadIdx.x & 63;
    int wave = threadIdx.x >> 6;
    if (lane == 0) wave_sums[wave] = s;
    __syncthreads();
    if (threadIdx.x == 0)
        out[0] = wave_sums[0] + wave_sums[1] + wave_sums[2] + wave_sums[3];
}

extern "C" void kernel_launch(void* const* d_in, const int* in_sizes, int n_in,
                              void* d_out, int out_size, void* d_ws, size_t ws_size,
                              hipStream_t stream) {
    const float* theta  = (const float*)d_in[0];
    const float* U_pred = (const float*)d_in[1];
    const float* U_true = (const float*)d_in[2];
    float* out = (float*)d_out;
    float* partial = (float*)d_ws;  // NBLK floats

    gauge_loss_kernel<<<NBLK, 256, 0, stream>>>(theta, U_pred, U_true, partial);
    reduce_kernel<<<1, 256, 0, stream>>>(partial, out);
}